// Round 6
// baseline (143.057 us; speedup 1.0000x reference)
//
#include <hip/hip_runtime.h>
#include <math.h>

#define B_ 16
#define C_ 64
#define HW_ 4096          // 64*64
#define PHW_ 1024         // pooled 32*32

typedef __attribute__((ext_vector_type(8))) short bf8;    // 8 bf16 = 4 VGPR (MFMA A/B)
typedef __attribute__((ext_vector_type(16))) float fv16;  // 16 f32 (MFMA C/D 32x32)

union FU { bf8 v; unsigned u[4]; };

__device__ inline unsigned short f2bf(float f) {          // RNE f32->bf16
    unsigned u = __float_as_uint(f);
    return (unsigned short)((u + 0x7FFFu + ((u >> 16) & 1u)) >> 16);
}
__device__ inline unsigned packbf(float a, float b) {     // two f32 -> packed bf16x2 (RNE)
    return (unsigned)f2bf(a) | ((unsigned)f2bf(b) << 16);
}
__device__ inline unsigned packtr(float a, float b) {     // truncating pack (fast path)
    return (__float_as_uint(a) >> 16) | (__float_as_uint(b) & 0xFFFF0000u);
}

// ---------------------------------------------------------------------------
// Kernel 1: fused 1x1 convs + 2x2 maxpool (UNCHANGED from R5 — control).
// ---------------------------------------------------------------------------
__global__ __launch_bounds__(256) void conv_stage(
    const float* __restrict__ x,
    const float* __restrict__ Wt,   // [8][64]
    const float* __restrict__ Wp,   // [8][64]
    const float* __restrict__ Wg,   // [32][64]
    float* __restrict__ theta,      // [B][8][HW]
    unsigned short* __restrict__ phi_pack,
    unsigned short* __restrict__ g_pack)
{
    __shared__ float sx[64][128];     // 32 KB
    __shared__ float pool2[40][33];   // pooled phi/g for the pack phase

    const int t  = threadIdx.x;
    const int b  = blockIdx.x >> 5;
    const int h2 = blockIdx.x & 31;     // pooled row (covers image rows 2h2, 2h2+1)

    const float* xbase = x + (size_t)b * C_ * HW_ + h2 * 128;
    for (int f = t; f < 2048; f += 256) {
        int c = f >> 5, j4 = f & 31;
        *(float4*)&sx[c][j4 * 4] = *(const float4*)&xbase[(size_t)c * HW_ + j4 * 4];
    }
    __syncthreads();

    const int wv   = __builtin_amdgcn_readfirstlane(t >> 6);   // SGPR wave id
    const int lane = t & 63;
    const int chbase = wv * 12;

    const float* wrow[12];
#pragma unroll
    for (int j = 0; j < 12; j++) {
        int gch = chbase + j;
        wrow[j] = (gch < 8) ? (Wt + gch * 64)
                : (gch < 16) ? (Wp + (gch - 8) * 64)
                             : (Wg + (gch - 16) * 64);
    }

    float acc[12][2];
#pragma unroll
    for (int j = 0; j < 12; j++) { acc[j][0] = 0.f; acc[j][1] = 0.f; }

    for (int c = 0; c < 64; c++) {
        float2 xv = *(const float2*)&sx[c][2 * lane];
#pragma unroll
        for (int j = 0; j < 12; j++) {
            float w = wrow[j][c];          // s_load, broadcast operand
            acc[j][0] += w * xv.x;
            acc[j][1] += w * xv.y;
        }
    }

    if (wv == 0) {
        float* tp = theta + (size_t)b * 8 * HW_ + h2 * 128 + 2 * lane;
#pragma unroll
        for (int j = 0; j < 8; j++)
            *(float2*)&tp[(size_t)j * HW_] = make_float2(acc[j][0], acc[j][1]);
    }

#pragma unroll
    for (int j = 0; j < 12; j++) {
        int gch = chbase + j;
        if (gch >= 8) {
            float hm = fmaxf(acc[j][0], acc[j][1]);
            float pm = fmaxf(hm, __shfl_xor(hm, 32));
            if (lane < 32) pool2[gch - 8][lane] = pm;   // pch 0-7 phi, 8-39 g
        }
    }
    __syncthreads();

    if (t < 64) {
        unsigned u0 = 0, u1 = 0, u2 = 0, u3 = 0;
        if (t < 32) {
            float v[8];
#pragma unroll
            for (int j = 0; j < 8; j++) v[j] = pool2[j][t];
            u0 = packbf(v[0], v[1]); u1 = packbf(v[2], v[3]);
            u2 = packbf(v[4], v[5]); u3 = packbf(v[6], v[7]);
        }
        uint4 pkt = make_uint4(u0, u1, u2, u3);
        *(uint4*)(phi_pack + ((size_t)((b * 32 + h2) * 64 + t)) * 8) = pkt;
    } else if (t < 192) {
        const int tt  = t - 64;
        const int ktl = tt >> 6;         // 0..1 (kt16 within this pooled row)
        const int ln  = tt & 63;
        const int c   = ln & 31;
        const int hh  = ln >> 5;
        float v[8];
#pragma unroll
        for (int j = 0; j < 8; j++) v[j] = pool2[8 + c][ktl * 16 + hh * 8 + j];
        uint4 pkt = make_uint4(packbf(v[0], v[1]), packbf(v[2], v[3]),
                               packbf(v[4], v[5]), packbf(v[6], v[7]));
        *(uint4*)(g_pack + ((size_t)((b * 64 + h2 * 2 + ktl) * 64 + ln)) * 8) = pkt;
    }
}

// ---------------------------------------------------------------------------
// Kernel 2: MFMA flash attention (UNCHANGED from R5 — control).
// ---------------------------------------------------------------------------
__global__ __launch_bounds__(256, 4) void attn_mfma(
    const float* __restrict__ theta_g,              // [B][8][HW]
    const unsigned short* __restrict__ phi_pack,
    const unsigned short* __restrict__ g_pack,
    const float* __restrict__ Wa,                   // [64][32]
    const float* __restrict__ x,
    const float* __restrict__ sigma,
    float* __restrict__ out)
{
    __shared__ float comb[4][64][17];

    const int t = threadIdx.x, wave = t >> 6, lane = t & 63;
    const int lo = lane & 31, hi = lane >> 5;
    const int qtile = blockIdx.x * 2 + (wave >> 1);
    const int khalf = wave & 1;
    const int b = qtile >> 7, qt = qtile & 127;
    const int qg = qt * 32 + lo;                    // this lane's query column

    FU tb; tb.u[0] = tb.u[1] = tb.u[2] = tb.u[3] = 0;
    if (hi == 0) {
        const float LOG2E = 1.4426950408889634f;
        float tv[8];
#pragma unroll
        for (int j = 0; j < 8; j++)
            tv[j] = theta_g[(((size_t)b * 8 + j) << 12) + qg] * LOG2E;
        tb.u[0] = packbf(tv[0], tv[1]); tb.u[1] = packbf(tv[2], tv[3]);
        tb.u[2] = packbf(tv[4], tv[5]); tb.u[3] = packbf(tv[6], tv[7]);
    }

    fv16 zf, acc;
#pragma unroll
    for (int r = 0; r < 16; r++) { zf[r] = 0.f; acc[r] = 0.f; }
    float ps = 0.f;

    const int kt0 = khalf * 16;
    const unsigned short* phip = phi_pack + ((size_t)((b * 32 + kt0) * 64 + lane)) * 8;
    const unsigned short* gp   = g_pack   + ((size_t)((b * 64 + kt0 * 2) * 64 + lane)) * 8;

#pragma unroll 2
    for (int i = 0; i < 16; i++) {
        FU pa, ga0, ga1;
        pa.v  = *(const bf8*)(phip + (size_t)i * 512);
        ga0.v = *(const bf8*)(gp + (size_t)i * 1024);
        ga1.v = *(const bf8*)(gp + (size_t)i * 1024 + 512);
        fv16 s = __builtin_amdgcn_mfma_f32_32x32x16_bf16(pa.v, tb.v, zf, 0, 0, 0);

        {
            unsigned pk[4], qk[4];
#pragma unroll
            for (int u = 0; u < 4; u++) {
                float p0 = __builtin_amdgcn_exp2f(s[2 * u]);
                float p1 = __builtin_amdgcn_exp2f(s[2 * u + 1]);
                ps += p0 + p1;
                pk[u] = packtr(p0, p1);
            }
#pragma unroll
            for (int u = 0; u < 4; u++) qk[u] = (unsigned)__shfl_xor((int)pk[u], 32);
            FU pb;
            pb.u[0] = hi ? qk[2] : pk[0]; pb.u[1] = hi ? qk[3] : pk[1];
            pb.u[2] = hi ? pk[2] : qk[0]; pb.u[3] = hi ? pk[3] : qk[1];
            acc = __builtin_amdgcn_mfma_f32_32x32x16_bf16(ga0.v, pb.v, acc, 0, 0, 0);
        }
        {
            unsigned pk[4], qk[4];
#pragma unroll
            for (int u = 0; u < 4; u++) {
                float p0 = __builtin_amdgcn_exp2f(s[8 + 2 * u]);
                float p1 = __builtin_amdgcn_exp2f(s[9 + 2 * u]);
                ps += p0 + p1;
                pk[u] = packtr(p0, p1);
            }
#pragma unroll
            for (int u = 0; u < 4; u++) qk[u] = (unsigned)__shfl_xor((int)pk[u], 32);
            FU pb;
            pb.u[0] = hi ? qk[2] : pk[0]; pb.u[1] = hi ? qk[3] : pk[1];
            pb.u[2] = hi ? pk[2] : qk[0]; pb.u[3] = hi ? pk[3] : qk[1];
            acc = __builtin_amdgcn_mfma_f32_32x32x16_bf16(ga1.v, pb.v, acc, 0, 0, 0);
        }
    }

#pragma unroll
    for (int r = 0; r < 16; r++) comb[wave][lane][r] = acc[r];
    comb[wave][lane][16] = ps;
    __syncthreads();
    const int pw = wave ^ 1;
#pragma unroll
    for (int r = 0; r < 16; r++) acc[r] += comb[pw][lane][r];
    ps += comb[pw][lane][16];

    float lsum = ps + __shfl_xor(ps, 32);
    float inv = 1.f / lsum;

    float on[16];
#pragma unroll
    for (int r = 0; r < 16; r++) on[r] = acc[r] * inv;
    unsigned pk[8], qk[8];
#pragma unroll
    for (int i = 0; i < 8; i++) pk[i] = packtr(on[2 * i], on[2 * i + 1]);
#pragma unroll
    for (int i = 0; i < 8; i++) qk[i] = (unsigned)__shfl_xor((int)pk[i], 32);
    FU ob0, ob1;
    ob0.u[0] = hi ? qk[2] : pk[0]; ob0.u[1] = hi ? qk[3] : pk[1];
    ob0.u[2] = hi ? pk[2] : qk[0]; ob0.u[3] = hi ? pk[3] : qk[1];
    ob1.u[0] = hi ? qk[6] : pk[4]; ob1.u[1] = hi ? qk[7] : pk[5];
    ob1.u[2] = hi ? pk[6] : qk[4]; ob1.u[3] = hi ? pk[7] : qk[5];

    FU wa0, wa1;
    {
        const float* wr = Wa + (khalf * 32 + lo) * 32;
#pragma unroll
        for (int ktw = 0; ktw < 2; ktw++) {
            float w8[8];
#pragma unroll
            for (int j = 0; j < 8; j++) w8[j] = wr[ktw * 16 + hi * 8 + j];
            FU f;
            f.u[0] = packbf(w8[0], w8[1]); f.u[1] = packbf(w8[2], w8[3]);
            f.u[2] = packbf(w8[4], w8[5]); f.u[3] = packbf(w8[6], w8[7]);
            if (ktw == 0) wa0 = f; else wa1 = f;
        }
    }
    fv16 d2 = __builtin_amdgcn_mfma_f32_32x32x16_bf16(wa0.v, ob0.v, zf, 0, 0, 0);
    d2 = __builtin_amdgcn_mfma_f32_32x32x16_bf16(wa1.v, ob1.v, d2, 0, 0, 0);

    const float sig = sigma[0];
#pragma unroll
    for (int r = 0; r < 16; r++) {
        int row = (r & 3) + ((r >> 2) << 3) + (hi << 2);
        int o = khalf * 32 + row;
        size_t idx = (((size_t)b * 64 + o) << 12) + qg;
        out[idx] = x[idx] + sig * d2[r];
    }
}

// ---------------------------------------------------------------------------
// MEASUREMENT ROUND: attn_mfma is launched 3x (idempotent: same inputs, same
// deterministic output each time; graph-safe; same work every call). With
// dur_R5 = F + conv + attn and dur_R6 = F + conv + 3*attn + 2*gap:
//   attn + gap = (dur_R6 - dur_R5) / 2.
// This splits the ~61 us of non-fill time between the two kernels, which are
// both below rocprof's top-5 cutoff (the 44 us ws-poison fills) and therefore
// invisible to the counters. Next round reverts to single-launch and attacks
// whichever kernel the delta implicates.
// ---------------------------------------------------------------------------
extern "C" void kernel_launch(void* const* d_in, const int* in_sizes, int n_in,
                              void* d_out, int out_size, void* d_ws, size_t ws_size,
                              hipStream_t stream) {
    const float* x     = (const float*)d_in[0];
    const float* Wt    = (const float*)d_in[1];
    const float* Wp    = (const float*)d_in[2];
    const float* Wg    = (const float*)d_in[3];
    const float* Wa    = (const float*)d_in[4];
    const float* sigma = (const float*)d_in[5];
    float* out = (float*)d_out;

    // ws layout: theta fp32 (2 MB) | phi_pack bf16 (512 KB) | g_pack bf16 (1 MB)
    float* theta = (float*)d_ws;                                  // 524288 floats
    unsigned short* phi_pack = (unsigned short*)(theta + (size_t)B_ * 8 * HW_);
    unsigned short* g_pack   = phi_pack + (size_t)B_ * 32 * 64 * 8;

    conv_stage<<<512, 256, 0, stream>>>(x, Wt, Wp, Wg, theta, phi_pack, g_pack);
    attn_mfma<<<1024, 256, 0, stream>>>(theta, phi_pack, g_pack, Wa, x, sigma, out);
    attn_mfma<<<1024, 256, 0, stream>>>(theta, phi_pack, g_pack, Wa, x, sigma, out);
    attn_mfma<<<1024, 256, 0, stream>>>(theta, phi_pack, g_pack, Wa, x, sigma, out);
}

// Round 7
// 103.302 us; speedup vs baseline: 1.3848x; 1.3848x over previous
//
#include <hip/hip_runtime.h>
#include <math.h>

#define B_ 16
#define C_ 64
#define HW_ 4096          // 64*64
#define PHW_ 1024         // pooled 32*32

typedef __attribute__((ext_vector_type(8))) short bf8;    // 8 bf16 = 4 VGPR (MFMA A/B)
typedef __attribute__((ext_vector_type(16))) float fv16;  // 16 f32 (MFMA C/D 32x32)

union FU { bf8 v; unsigned u[4]; };

__device__ inline unsigned short f2bf(float f) {          // RNE f32->bf16
    unsigned u = __float_as_uint(f);
    return (unsigned short)((u + 0x7FFFu + ((u >> 16) & 1u)) >> 16);
}
__device__ inline unsigned packbf(float a, float b) {     // two f32 -> packed bf16x2 (RNE)
    return (unsigned)f2bf(a) | ((unsigned)f2bf(b) << 16);
}
__device__ inline unsigned packtr(float a, float b) {     // truncating pack (fast path)
    return (__float_as_uint(a) >> 16) | (__float_as_uint(b) & 0xFFFF0000u);
}

// ---------------------------------------------------------------------------
// Kernel 1: fused 1x1 convs + 2x2 maxpool — REVERTED to the R4 structure
// (LDS-staged weights; phase1 theta, phase2 pooled phi/g, bf16 pack phase).
// R5's SGPR-weight variant regressed conv ~15 -> ~40 us: 768 in-loop s_loads
// share lgkmcnt with ds_reads -> per-iter full drains, unhidden at 2 waves/
// SIMD. This structure measured ~13-15 us in R3/R4 budgets.
// ---------------------------------------------------------------------------
__global__ __launch_bounds__(256) void conv_stage(
    const float* __restrict__ x,
    const float* __restrict__ Wt,   // [8][64]
    const float* __restrict__ Wp,   // [8][64]
    const float* __restrict__ Wg,   // [32][64]
    float* __restrict__ theta,      // [B][8][HW]
    unsigned short* __restrict__ phi_pack,
    unsigned short* __restrict__ g_pack)
{
    __shared__ float sx[64][128];     // 32 KB
    __shared__ float sw[64][48];      // 12 KB
    __shared__ float pool2[40][33];   // pooled phi/g staging for pack phase

    const int t  = threadIdx.x;
    const int b  = blockIdx.x >> 5;
    const int h2 = blockIdx.x & 31;     // pooled row

    for (int i = t; i < 3072; i += 256) {
        int c = i / 48, ch = i - c * 48;
        float v;
        if (ch < 8)       v = Wt[ch * 64 + c];
        else if (ch < 16) v = Wp[(ch - 8) * 64 + c];
        else              v = Wg[(ch - 16) * 64 + c];
        sw[c][ch] = v;
    }
    const float* xbase = x + (size_t)b * C_ * HW_ + h2 * 128;
    for (int f = t; f < 2048; f += 256) {
        int c = f >> 5, j4 = f & 31;
        *(float4*)&sx[c][j4 * 4] = *(const float4*)&xbase[(size_t)c * HW_ + j4 * 4];
    }
    __syncthreads();

    // phase 1: theta (full res), 128 px x 2 channel-halves
    {
        const int px  = t & 127;
        const int ch0 = (t >> 7) * 4;
        float a0 = 0.f, a1 = 0.f, a2 = 0.f, a3 = 0.f;
        for (int c = 0; c < 64; c++) {
            float xv = sx[c][px];
            float4 wv = *(const float4*)&sw[c][ch0];
            a0 += wv.x * xv; a1 += wv.y * xv; a2 += wv.z * xv; a3 += wv.w * xv;
        }
        float* tp = theta + (size_t)b * 8 * HW_ + h2 * 128 + px;
        tp[(size_t)(ch0 + 0) * HW_] = a0;
        tp[(size_t)(ch0 + 1) * HW_] = a1;
        tp[(size_t)(ch0 + 2) * HW_] = a2;
        tp[(size_t)(ch0 + 3) * HW_] = a3;
    }

    // phase 2: pooled phi/g -> pool2 LDS. 32 pooled-cols x 8 groups of 5 ch.
    {
        const int p   = t & 31;
        const int grp = t >> 5;
        float a[5][4];
#pragma unroll
        for (int j = 0; j < 5; j++)
#pragma unroll
            for (int u = 0; u < 4; u++) a[j][u] = 0.f;

        for (int c = 0; c < 64; c++) {
            float2 xa  = *(const float2*)&sx[c][2 * p];
            float2 xb2 = *(const float2*)&sx[c][64 + 2 * p];
#pragma unroll
            for (int j = 0; j < 5; j++) {
                float wv = sw[c][8 + grp * 5 + j];
                a[j][0] += wv * xa.x;  a[j][1] += wv * xa.y;
                a[j][2] += wv * xb2.x; a[j][3] += wv * xb2.y;
            }
        }
#pragma unroll
        for (int j = 0; j < 5; j++) {
            float m = fmaxf(fmaxf(a[j][0], a[j][1]), fmaxf(a[j][2], a[j][3]));
            pool2[grp * 5 + j][p] = m;   // pch 0-7 phi, 8-39 g
        }
    }
    __syncthreads();

    // pack phase: write bf16 MFMA fragments
    if (t < 64) {
        unsigned u0 = 0, u1 = 0, u2 = 0, u3 = 0;
        if (t < 32) {
            float v[8];
#pragma unroll
            for (int j = 0; j < 8; j++) v[j] = pool2[j][t];
            u0 = packbf(v[0], v[1]); u1 = packbf(v[2], v[3]);
            u2 = packbf(v[4], v[5]); u3 = packbf(v[6], v[7]);
        }
        uint4 pkt = make_uint4(u0, u1, u2, u3);
        *(uint4*)(phi_pack + ((size_t)((b * 32 + h2) * 64 + t)) * 8) = pkt;
    } else if (t < 192) {
        const int tt  = t - 64;
        const int ktl = tt >> 6;         // 0..1 (kt16 within this pooled row)
        const int ln  = tt & 63;
        const int c   = ln & 31;
        const int hh  = ln >> 5;
        float v[8];
#pragma unroll
        for (int j = 0; j < 8; j++) v[j] = pool2[8 + c][ktl * 16 + hh * 8 + j];
        uint4 pkt = make_uint4(packbf(v[0], v[1]), packbf(v[2], v[3]),
                               packbf(v[4], v[5]), packbf(v[6], v[7]));
        *(uint4*)(g_pack + ((size_t)((b * 64 + h2 * 2 + ktl) * 64 + ln)) * 8) = pkt;
    }
}

// ---------------------------------------------------------------------------
// Kernel 2: MFMA flash attention (UNCHANGED from R5 — measured ~16 us).
// ---------------------------------------------------------------------------
__global__ __launch_bounds__(256, 4) void attn_mfma(
    const float* __restrict__ theta_g,              // [B][8][HW]
    const unsigned short* __restrict__ phi_pack,
    const unsigned short* __restrict__ g_pack,
    const float* __restrict__ Wa,                   // [64][32]
    const float* __restrict__ x,
    const float* __restrict__ sigma,
    float* __restrict__ out)
{
    __shared__ float comb[4][64][17];

    const int t = threadIdx.x, wave = t >> 6, lane = t & 63;
    const int lo = lane & 31, hi = lane >> 5;
    const int qtile = blockIdx.x * 2 + (wave >> 1);
    const int khalf = wave & 1;
    const int b = qtile >> 7, qt = qtile & 127;
    const int qg = qt * 32 + lo;                    // this lane's query column

    FU tb; tb.u[0] = tb.u[1] = tb.u[2] = tb.u[3] = 0;
    if (hi == 0) {
        const float LOG2E = 1.4426950408889634f;
        float tv[8];
#pragma unroll
        for (int j = 0; j < 8; j++)
            tv[j] = theta_g[(((size_t)b * 8 + j) << 12) + qg] * LOG2E;
        tb.u[0] = packbf(tv[0], tv[1]); tb.u[1] = packbf(tv[2], tv[3]);
        tb.u[2] = packbf(tv[4], tv[5]); tb.u[3] = packbf(tv[6], tv[7]);
    }

    fv16 zf, acc;
#pragma unroll
    for (int r = 0; r < 16; r++) { zf[r] = 0.f; acc[r] = 0.f; }
    float ps = 0.f;

    const int kt0 = khalf * 16;
    const unsigned short* phip = phi_pack + ((size_t)((b * 32 + kt0) * 64 + lane)) * 8;
    const unsigned short* gp   = g_pack   + ((size_t)((b * 64 + kt0 * 2) * 64 + lane)) * 8;

#pragma unroll 2
    for (int i = 0; i < 16; i++) {
        FU pa, ga0, ga1;
        pa.v  = *(const bf8*)(phip + (size_t)i * 512);
        ga0.v = *(const bf8*)(gp + (size_t)i * 1024);
        ga1.v = *(const bf8*)(gp + (size_t)i * 1024 + 512);
        fv16 s = __builtin_amdgcn_mfma_f32_32x32x16_bf16(pa.v, tb.v, zf, 0, 0, 0);

        {
            unsigned pk[4], qk[4];
#pragma unroll
            for (int u = 0; u < 4; u++) {
                float p0 = __builtin_amdgcn_exp2f(s[2 * u]);
                float p1 = __builtin_amdgcn_exp2f(s[2 * u + 1]);
                ps += p0 + p1;
                pk[u] = packtr(p0, p1);
            }
#pragma unroll
            for (int u = 0; u < 4; u++) qk[u] = (unsigned)__shfl_xor((int)pk[u], 32);
            FU pb;
            pb.u[0] = hi ? qk[2] : pk[0]; pb.u[1] = hi ? qk[3] : pk[1];
            pb.u[2] = hi ? pk[2] : qk[0]; pb.u[3] = hi ? pk[3] : qk[1];
            acc = __builtin_amdgcn_mfma_f32_32x32x16_bf16(ga0.v, pb.v, acc, 0, 0, 0);
        }
        {
            unsigned pk[4], qk[4];
#pragma unroll
            for (int u = 0; u < 4; u++) {
                float p0 = __builtin_amdgcn_exp2f(s[8 + 2 * u]);
                float p1 = __builtin_amdgcn_exp2f(s[9 + 2 * u]);
                ps += p0 + p1;
                pk[u] = packtr(p0, p1);
            }
#pragma unroll
            for (int u = 0; u < 4; u++) qk[u] = (unsigned)__shfl_xor((int)pk[u], 32);
            FU pb;
            pb.u[0] = hi ? qk[2] : pk[0]; pb.u[1] = hi ? qk[3] : pk[1];
            pb.u[2] = hi ? pk[2] : qk[0]; pb.u[3] = hi ? pk[3] : qk[1];
            acc = __builtin_amdgcn_mfma_f32_32x32x16_bf16(ga1.v, pb.v, acc, 0, 0, 0);
        }
    }

#pragma unroll
    for (int r = 0; r < 16; r++) comb[wave][lane][r] = acc[r];
    comb[wave][lane][16] = ps;
    __syncthreads();
    const int pw = wave ^ 1;
#pragma unroll
    for (int r = 0; r < 16; r++) acc[r] += comb[pw][lane][r];
    ps += comb[pw][lane][16];

    float lsum = ps + __shfl_xor(ps, 32);
    float inv = 1.f / lsum;

    float on[16];
#pragma unroll
    for (int r = 0; r < 16; r++) on[r] = acc[r] * inv;
    unsigned pk[8], qk[8];
#pragma unroll
    for (int i = 0; i < 8; i++) pk[i] = packtr(on[2 * i], on[2 * i + 1]);
#pragma unroll
    for (int i = 0; i < 8; i++) qk[i] = (unsigned)__shfl_xor((int)pk[i], 32);
    FU ob0, ob1;
    ob0.u[0] = hi ? qk[2] : pk[0]; ob0.u[1] = hi ? qk[3] : pk[1];
    ob0.u[2] = hi ? pk[2] : qk[0]; ob0.u[3] = hi ? pk[3] : qk[1];
    ob1.u[0] = hi ? qk[6] : pk[4]; ob1.u[1] = hi ? qk[7] : pk[5];
    ob1.u[2] = hi ? pk[6] : qk[4]; ob1.u[3] = hi ? pk[7] : qk[5];

    FU wa0, wa1;
    {
        const float* wr = Wa + (khalf * 32 + lo) * 32;
#pragma unroll
        for (int ktw = 0; ktw < 2; ktw++) {
            float w8[8];
#pragma unroll
            for (int j = 0; j < 8; j++) w8[j] = wr[ktw * 16 + hi * 8 + j];
            FU f;
            f.u[0] = packbf(w8[0], w8[1]); f.u[1] = packbf(w8[2], w8[3]);
            f.u[2] = packbf(w8[4], w8[5]); f.u[3] = packbf(w8[6], w8[7]);
            if (ktw == 0) wa0 = f; else wa1 = f;
        }
    }
    fv16 d2 = __builtin_amdgcn_mfma_f32_32x32x16_bf16(wa0.v, ob0.v, zf, 0, 0, 0);
    d2 = __builtin_amdgcn_mfma_f32_32x32x16_bf16(wa1.v, ob1.v, d2, 0, 0, 0);

    const float sig = sigma[0];
#pragma unroll
    for (int r = 0; r < 16; r++) {
        int row = (r & 3) + ((r >> 2) << 3) + (hi << 2);
        int o = khalf * 32 + row;
        size_t idx = (((size_t)b * 64 + o) << 12) + qg;
        out[idx] = x[idx] + sig * d2[r];
    }
}

// ---------------------------------------------------------------------------
extern "C" void kernel_launch(void* const* d_in, const int* in_sizes, int n_in,
                              void* d_out, int out_size, void* d_ws, size_t ws_size,
                              hipStream_t stream) {
    const float* x     = (const float*)d_in[0];
    const float* Wt    = (const float*)d_in[1];
    const float* Wp    = (const float*)d_in[2];
    const float* Wg    = (const float*)d_in[3];
    const float* Wa    = (const float*)d_in[4];
    const float* sigma = (const float*)d_in[5];
    float* out = (float*)d_out;

    // ws layout: theta fp32 (2 MB) | phi_pack bf16 (512 KB) | g_pack bf16 (1 MB)
    float* theta = (float*)d_ws;                                  // 524288 floats
    unsigned short* phi_pack = (unsigned short*)(theta + (size_t)B_ * 8 * HW_);
    unsigned short* g_pack   = phi_pack + (size_t)B_ * 32 * 64 * 8;

    conv_stage<<<512, 256, 0, stream>>>(x, Wt, Wp, Wg, theta, phi_pack, g_pack);
    attn_mfma<<<1024, 256, 0, stream>>>(theta, phi_pack, g_pack, Wa, x, sigma, out);
}

// Round 8
// 99.883 us; speedup vs baseline: 1.4322x; 1.0342x over previous
//
#include <hip/hip_runtime.h>
#include <math.h>

#define B_ 16
#define C_ 64
#define HW_ 4096          // 64*64
#define PHW_ 1024         // pooled 32*32

typedef __attribute__((ext_vector_type(8))) short bf8;    // 8 bf16 = 4 VGPR (MFMA A/B)
typedef __attribute__((ext_vector_type(16))) float fv16;  // 16 f32 (MFMA C/D 32x32)

union FU { bf8 v; unsigned u[4]; };

__device__ inline unsigned short f2bf(float f) {          // RNE f32->bf16
    unsigned u = __float_as_uint(f);
    return (unsigned short)((u + 0x7FFFu + ((u >> 16) & 1u)) >> 16);
}
__device__ inline unsigned packbf(float a, float b) {     // two f32 -> packed bf16x2 (RNE)
    return (unsigned)f2bf(a) | ((unsigned)f2bf(b) << 16);
}
__device__ inline unsigned packtr(float a, float b) {     // truncating pack (fast path)
    return (__float_as_uint(a) >> 16) | (__float_as_uint(b) & 0xFFFF0000u);
}

// ---------------------------------------------------------------------------
// Kernel 1 (NEW): MFMA conv. O[ch][px] = W[ch][c] * x[c][px] as 32x32x16 bf16
// MFMA: A = W (ch in lanes), B = x (px in lanes), D[m=ch][n=px]. Per block
// (b, pooled row h2): x tile [64c][128px] fp32 in LDS; wave w owns px-subtile
// w*32..+31. 2 ch-tiles (0-31, 32-47+pad) x 4 k-steps = 8 MFMA/wave.
// B-frag: 8x ds_read_b32, lane=px -> consecutive banks, conflict-free.
// theta (ch 0-7) stored from C-regs; ch 8-47 hmax via shfl_xor(1), cross-row
// max via poolh LDS, then the (unchanged) bf16 pack phase.
// ---------------------------------------------------------------------------
__global__ __launch_bounds__(256) void conv_stage(
    const float* __restrict__ x,
    const float* __restrict__ Wt,   // [8][64]
    const float* __restrict__ Wp,   // [8][64]
    const float* __restrict__ Wg,   // [32][64]
    float* __restrict__ theta,      // [B][8][HW]
    unsigned short* __restrict__ phi_pack,
    unsigned short* __restrict__ g_pack)
{
    __shared__ float sx[64][128];        // 32 KB, [c][px]
    __shared__ float poolh[2][40][33];   // per-image-row hmax, 10.3 KB

    const int t  = threadIdx.x;
    const int b  = blockIdx.x >> 5;
    const int h2 = blockIdx.x & 31;      // pooled row (image rows 2h2, 2h2+1)

    // stage x tile: 2048 float4, coalesced
    const float* xbase = x + (size_t)b * C_ * HW_ + h2 * 128;
    for (int f = t; f < 2048; f += 256) {
        int c = f >> 5, j4 = f & 31;
        *(float4*)&sx[c][j4 * 4] = *(const float4*)&xbase[(size_t)c * HW_ + j4 * 4];
    }

    const int wv = t >> 6, lane = t & 63, lo = lane & 31, hi = lane >> 5;

    // A-frags: W in bf16, A[m=ch=lo][k=c], k = cs*16 + hi*8 + j. Built from
    // global (L2-hot, 12 KB total) while staging is in flight.
    FU wa[2][4];
    {
        const float* r0 = (lo < 8)  ? (Wt + lo * 64)
                        : (lo < 16) ? (Wp + (lo - 8) * 64)
                                    : (Wg + (lo - 16) * 64);
        const float* r1 = Wg + ((lo < 16) ? (16 + lo) : 0) * 64;  // pad lanes zeroed below
#pragma unroll
        for (int cs = 0; cs < 4; cs++) {
            const int c0 = cs * 16 + hi * 8;
            float4 a0 = *(const float4*)&r0[c0];
            float4 b0 = *(const float4*)&r0[c0 + 4];
            wa[0][cs].u[0] = packbf(a0.x, a0.y); wa[0][cs].u[1] = packbf(a0.z, a0.w);
            wa[0][cs].u[2] = packbf(b0.x, b0.y); wa[0][cs].u[3] = packbf(b0.z, b0.w);
            float4 a1 = *(const float4*)&r1[c0];
            float4 b1 = *(const float4*)&r1[c0 + 4];
            if (lo >= 16) { a1 = make_float4(0.f,0.f,0.f,0.f); b1 = make_float4(0.f,0.f,0.f,0.f); }
            wa[1][cs].u[0] = packbf(a1.x, a1.y); wa[1][cs].u[1] = packbf(a1.z, a1.w);
            wa[1][cs].u[2] = packbf(b1.x, b1.y); wa[1][cs].u[3] = packbf(b1.z, b1.w);
        }
    }
    __syncthreads();

    fv16 acc0, acc1;
#pragma unroll
    for (int r = 0; r < 16; r++) { acc0[r] = 0.f; acc1[r] = 0.f; }

    const int px = wv * 32 + lo;         // local pixel 0..127
#pragma unroll
    for (int cs = 0; cs < 4; cs++) {
        // B[n=px][k], k = cs*16 + hi*8 + j: 8 conflict-free ds_read_b32
        const float* sp = &sx[cs * 16 + hi * 8][px];
        float v[8];
#pragma unroll
        for (int j = 0; j < 8; j++) v[j] = sp[j * 128];
        FU xb;
        xb.u[0] = packbf(v[0], v[1]); xb.u[1] = packbf(v[2], v[3]);
        xb.u[2] = packbf(v[4], v[5]); xb.u[3] = packbf(v[6], v[7]);
        acc0 = __builtin_amdgcn_mfma_f32_32x32x16_bf16(wa[0][cs].v, xb.v, acc0, 0, 0, 0);
        acc1 = __builtin_amdgcn_mfma_f32_32x32x16_bf16(wa[1][cs].v, xb.v, acc1, 0, 0, 0);
    }

    // theta (ch 0-7 = tile0 regs 0-3, m = r + 4*hi), coalesced dword stores
    {
        float* tp = theta + (size_t)b * 8 * HW_ + h2 * 128 + px;
#pragma unroll
        for (int r = 0; r < 4; r++) tp[(size_t)(r + 4 * hi) * HW_] = acc0[r];
    }

    // pooled channels: horizontal max via shfl_xor(1), stash per-image-row
    const int prow = wv >> 1;                   // image row within pooled row
    const int pcol = (wv & 1) * 16 + (lo >> 1); // pooled column 0..31
#pragma unroll
    for (int r = 4; r < 16; r++) {              // tile0: ch 8..31 -> pch 0..23
        float vv = acc0[r];
        float hm = fmaxf(vv, __shfl_xor(vv, 1));
        if ((lane & 1) == 0) {
            int m = (r & 3) + 8 * (r >> 2) + 4 * hi;   // 8..31
            poolh[prow][m - 8][pcol] = hm;
        }
    }
#pragma unroll
    for (int r = 0; r < 8; r++) {               // tile1: ch 32..47 -> pch 24..39
        float vv = acc1[r];
        float hm = fmaxf(vv, __shfl_xor(vv, 1));
        if ((lane & 1) == 0) {
            int m1 = (r & 3) + 8 * (r >> 2) + 4 * hi;  // 0..15
            poolh[prow][24 + m1][pcol] = hm;
        }
    }
    __syncthreads();

    // pack phase (unchanged layouts; reads = vertical max of the two rows)
    if (t < 64) {
        unsigned u0 = 0, u1 = 0, u2 = 0, u3 = 0;
        if (t < 32) {
            float v[8];
#pragma unroll
            for (int j = 0; j < 8; j++)
                v[j] = fmaxf(poolh[0][j][t], poolh[1][j][t]);
            u0 = packbf(v[0], v[1]); u1 = packbf(v[2], v[3]);
            u2 = packbf(v[4], v[5]); u3 = packbf(v[6], v[7]);
        }
        uint4 pkt = make_uint4(u0, u1, u2, u3);
        *(uint4*)(phi_pack + ((size_t)((b * 32 + h2) * 64 + t)) * 8) = pkt;
    } else if (t < 192) {
        const int tt  = t - 64;
        const int ktl = tt >> 6;         // 0..1 (kt16 within this pooled row)
        const int ln  = tt & 63;
        const int c   = ln & 31;
        const int hh  = ln >> 5;
        float v[8];
#pragma unroll
        for (int j = 0; j < 8; j++) {
            int p = ktl * 16 + hh * 8 + j;
            v[j] = fmaxf(poolh[0][8 + c][p], poolh[1][8 + c][p]);
        }
        uint4 pkt = make_uint4(packbf(v[0], v[1]), packbf(v[2], v[3]),
                               packbf(v[4], v[5]), packbf(v[6], v[7]));
        *(uint4*)(g_pack + ((size_t)((b * 64 + h2 * 2 + ktl) * 64 + ln)) * 8) = pkt;
    }
}

// ---------------------------------------------------------------------------
// Kernel 2: MFMA flash attention (UNCHANGED from R5 — warm-measured ~16 us).
// ---------------------------------------------------------------------------
__global__ __launch_bounds__(256, 4) void attn_mfma(
    const float* __restrict__ theta_g,              // [B][8][HW]
    const unsigned short* __restrict__ phi_pack,
    const unsigned short* __restrict__ g_pack,
    const float* __restrict__ Wa,                   // [64][32]
    const float* __restrict__ x,
    const float* __restrict__ sigma,
    float* __restrict__ out)
{
    __shared__ float comb[4][64][17];

    const int t = threadIdx.x, wave = t >> 6, lane = t & 63;
    const int lo = lane & 31, hi = lane >> 5;
    const int qtile = blockIdx.x * 2 + (wave >> 1);
    const int khalf = wave & 1;
    const int b = qtile >> 7, qt = qtile & 127;
    const int qg = qt * 32 + lo;                    // this lane's query column

    FU tb; tb.u[0] = tb.u[1] = tb.u[2] = tb.u[3] = 0;
    if (hi == 0) {
        const float LOG2E = 1.4426950408889634f;
        float tv[8];
#pragma unroll
        for (int j = 0; j < 8; j++)
            tv[j] = theta_g[(((size_t)b * 8 + j) << 12) + qg] * LOG2E;
        tb.u[0] = packbf(tv[0], tv[1]); tb.u[1] = packbf(tv[2], tv[3]);
        tb.u[2] = packbf(tv[4], tv[5]); tb.u[3] = packbf(tv[6], tv[7]);
    }

    fv16 zf, acc;
#pragma unroll
    for (int r = 0; r < 16; r++) { zf[r] = 0.f; acc[r] = 0.f; }
    float ps = 0.f;

    const int kt0 = khalf * 16;
    const unsigned short* phip = phi_pack + ((size_t)((b * 32 + kt0) * 64 + lane)) * 8;
    const unsigned short* gp   = g_pack   + ((size_t)((b * 64 + kt0 * 2) * 64 + lane)) * 8;

#pragma unroll 2
    for (int i = 0; i < 16; i++) {
        FU pa, ga0, ga1;
        pa.v  = *(const bf8*)(phip + (size_t)i * 512);
        ga0.v = *(const bf8*)(gp + (size_t)i * 1024);
        ga1.v = *(const bf8*)(gp + (size_t)i * 1024 + 512);
        fv16 s = __builtin_amdgcn_mfma_f32_32x32x16_bf16(pa.v, tb.v, zf, 0, 0, 0);

        {
            unsigned pk[4], qk[4];
#pragma unroll
            for (int u = 0; u < 4; u++) {
                float p0 = __builtin_amdgcn_exp2f(s[2 * u]);
                float p1 = __builtin_amdgcn_exp2f(s[2 * u + 1]);
                ps += p0 + p1;
                pk[u] = packtr(p0, p1);
            }
#pragma unroll
            for (int u = 0; u < 4; u++) qk[u] = (unsigned)__shfl_xor((int)pk[u], 32);
            FU pb;
            pb.u[0] = hi ? qk[2] : pk[0]; pb.u[1] = hi ? qk[3] : pk[1];
            pb.u[2] = hi ? pk[2] : qk[0]; pb.u[3] = hi ? pk[3] : qk[1];
            acc = __builtin_amdgcn_mfma_f32_32x32x16_bf16(ga0.v, pb.v, acc, 0, 0, 0);
        }
        {
            unsigned pk[4], qk[4];
#pragma unroll
            for (int u = 0; u < 4; u++) {
                float p0 = __builtin_amdgcn_exp2f(s[8 + 2 * u]);
                float p1 = __builtin_amdgcn_exp2f(s[9 + 2 * u]);
                ps += p0 + p1;
                pk[u] = packtr(p0, p1);
            }
#pragma unroll
            for (int u = 0; u < 4; u++) qk[u] = (unsigned)__shfl_xor((int)pk[u], 32);
            FU pb;
            pb.u[0] = hi ? qk[2] : pk[0]; pb.u[1] = hi ? qk[3] : pk[1];
            pb.u[2] = hi ? pk[2] : qk[0]; pb.u[3] = hi ? pk[3] : qk[1];
            acc = __builtin_amdgcn_mfma_f32_32x32x16_bf16(ga1.v, pb.v, acc, 0, 0, 0);
        }
    }

#pragma unroll
    for (int r = 0; r < 16; r++) comb[wave][lane][r] = acc[r];
    comb[wave][lane][16] = ps;
    __syncthreads();
    const int pw = wave ^ 1;
#pragma unroll
    for (int r = 0; r < 16; r++) acc[r] += comb[pw][lane][r];
    ps += comb[pw][lane][16];

    float lsum = ps + __shfl_xor(ps, 32);
    float inv = 1.f / lsum;

    float on[16];
#pragma unroll
    for (int r = 0; r < 16; r++) on[r] = acc[r] * inv;
    unsigned pk[8], qk[8];
#pragma unroll
    for (int i = 0; i < 8; i++) pk[i] = packtr(on[2 * i], on[2 * i + 1]);
#pragma unroll
    for (int i = 0; i < 8; i++) qk[i] = (unsigned)__shfl_xor((int)pk[i], 32);
    FU ob0, ob1;
    ob0.u[0] = hi ? qk[2] : pk[0]; ob0.u[1] = hi ? qk[3] : pk[1];
    ob0.u[2] = hi ? pk[2] : qk[0]; ob0.u[3] = hi ? pk[3] : qk[1];
    ob1.u[0] = hi ? qk[6] : pk[4]; ob1.u[1] = hi ? qk[7] : pk[5];
    ob1.u[2] = hi ? pk[6] : qk[4]; ob1.u[3] = hi ? pk[7] : qk[5];

    FU wa0, wa1;
    {
        const float* wr = Wa + (khalf * 32 + lo) * 32;
#pragma unroll
        for (int ktw = 0; ktw < 2; ktw++) {
            float w8[8];
#pragma unroll
            for (int j = 0; j < 8; j++) w8[j] = wr[ktw * 16 + hi * 8 + j];
            FU f;
            f.u[0] = packbf(w8[0], w8[1]); f.u[1] = packbf(w8[2], w8[3]);
            f.u[2] = packbf(w8[4], w8[5]); f.u[3] = packbf(w8[6], w8[7]);
            if (ktw == 0) wa0 = f; else wa1 = f;
        }
    }
    fv16 d2 = __builtin_amdgcn_mfma_f32_32x32x16_bf16(wa0.v, ob0.v, zf, 0, 0, 0);
    d2 = __builtin_amdgcn_mfma_f32_32x32x16_bf16(wa1.v, ob1.v, d2, 0, 0, 0);

    const float sig = sigma[0];
#pragma unroll
    for (int r = 0; r < 16; r++) {
        int row = (r & 3) + ((r >> 2) << 3) + (hi << 2);
        int o = khalf * 32 + row;
        size_t idx = (((size_t)b * 64 + o) << 12) + qg;
        out[idx] = x[idx] + sig * d2[r];
    }
}

// ---------------------------------------------------------------------------
extern "C" void kernel_launch(void* const* d_in, const int* in_sizes, int n_in,
                              void* d_out, int out_size, void* d_ws, size_t ws_size,
                              hipStream_t stream) {
    const float* x     = (const float*)d_in[0];
    const float* Wt    = (const float*)d_in[1];
    const float* Wp    = (const float*)d_in[2];
    const float* Wg    = (const float*)d_in[3];
    const float* Wa    = (const float*)d_in[4];
    const float* sigma = (const float*)d_in[5];
    float* out = (float*)d_out;

    // ws layout: theta fp32 (2 MB) | phi_pack bf16 (512 KB) | g_pack bf16 (1 MB)
    float* theta = (float*)d_ws;                                  // 524288 floats
    unsigned short* phi_pack = (unsigned short*)(theta + (size_t)B_ * 8 * HW_);
    unsigned short* g_pack   = phi_pack + (size_t)B_ * 32 * 64 * 8;

    conv_stage<<<512, 256, 0, stream>>>(x, Wt, Wp, Wg, theta, phi_pack, g_pack);
    attn_mfma<<<1024, 256, 0, stream>>>(theta, phi_pack, g_pack, Wa, x, sigma, out);
}